// Round 6
// baseline (313.119 us; speedup 1.0000x reference)
//
#include <hip/hip_runtime.h>
#include <hip/hip_cooperative_groups.h>
#include <math.h>

namespace cg = cooperative_groups;

#define NX 2048
#define NV 1024
static constexpr float DXf   = 1.0f / 2048.0f;
static constexpr float DVf   = 12.0f / 1024.0f;
static constexpr float DTf   = 0.001f;
static constexpr float INV_DX = 2048.0f;
static constexpr float INV_DV = 1024.0f / 12.0f;

__device__ __forceinline__ float minmod_f(float a, float b) {
    return (a * b > 0.0f) ? (a > 0.0f ? fminf(a, b) : fmaxf(a, b)) : 0.0f;
}

__device__ __forceinline__ float frcp(float x) {
    float r = __builtin_amdgcn_rcpf(x);
    return r * (2.0f - x * r);
}

// Vectorized MUSCL rhs for 4 contiguous cells j0..j0+3 (j0 % 4 == 0).
__device__ __forceinline__ void rhs4(const float* __restrict__ g, int i, int j0, float Ec,
                                     float4& f0v, float4& rv) {
    const float* rowc = g + i * NV;
    const float* rm1  = g + (((i - 1) & (NX - 1)) * NV);
    const float* rm2  = g + (((i - 2) & (NX - 1)) * NV);
    const float* rp1  = g + (((i + 1) & (NX - 1)) * NV);
    const float* rp2  = g + (((i + 2) & (NX - 1)) * NV);

    float4 c   = *(const float4*)(rowc + j0);
    float4 xm1 = *(const float4*)(rm1 + j0);
    float4 xm2 = *(const float4*)(rm2 + j0);
    float4 xp1 = *(const float4*)(rp1 + j0);
    float4 xp2 = *(const float4*)(rp2 + j0);
    float4 lm = make_float4(0.f, 0.f, 0.f, 0.f);
    float4 rp = make_float4(0.f, 0.f, 0.f, 0.f);
    if (j0 >= 4)      lm = *(const float4*)(rowc + j0 - 4);
    if (j0 <= NV - 8) rp = *(const float4*)(rowc + j0 + 4);

    float vals[8] = {lm.z, lm.w, c.x, c.y, c.z, c.w, rp.x, rp.y};
    const float* cc   = (const float*)&c;
    const float* am1  = (const float*)&xm1;
    const float* am2  = (const float*)&xm2;
    const float* ap1  = (const float*)&xp1;
    const float* ap2  = (const float*)&xp2;
    float* f0o = (float*)&f0v;
    float* ro  = (float*)&rv;

    #pragma unroll
    for (int k = 0; k < 4; ++k) {
        float f0  = cc[k];
        float fm1 = am1[k], fm2 = am2[k], fp1 = ap1[k], fp2 = ap2[k];

        float v = DVf * ((float)(j0 + k) + 0.5f) - 6.0f;
        float dm1 = fm1 - fm2, d0 = f0 - fm1, dp1 = fp1 - f0, dp2 = fp2 - fp1;
        float sm1 = minmod_f(dm1, d0);
        float s0  = minmod_f(d0, dp1);
        float sp1 = minmod_f(dp1, dp2);
        float PhiM, PhiP;
        if (v > 0.0f) {
            PhiM = (fm1 + 0.5f * sm1) * v;
            PhiP = (f0  + 0.5f * s0 ) * v;
        } else {
            PhiM = (f0  - 0.5f * s0 ) * v;
            PhiP = (fp1 - 0.5f * sp1) * v;
        }
        float vdfdx = (PhiP - PhiM) * INV_DX;

        float gm2 = vals[k], gm1 = vals[k + 1], gp1 = vals[k + 3], gp2 = vals[k + 4];
        float em1 = gm1 - gm2, e0 = f0 - gm1, ep1 = gp1 - f0, ep2 = gp2 - gp1;
        float tm1 = minmod_f(em1, e0);
        float t0  = minmod_f(e0, ep1);
        float tp1 = minmod_f(ep1, ep2);
        float GM, GP;
        if (Ec > 0.0f) {
            GM = (gm1 + 0.5f * tm1) * Ec;
            GP = (f0  + 0.5f * t0 ) * Ec;
        } else {
            GM = (f0  - 0.5f * t0 ) * Ec;
            GP = (gp1 - 0.5f * tp1) * Ec;
        }
        float Edfdv = (GP - GM) * INV_DV;

        f0o[k] = f0;
        ro[k]  = -vdfdx - Edfdv;
    }
}

// E[i] = DX*(P_i - W/NX), P_i = sum_{k<=i} rho_k, W = sum_k rho_k*(NX-k).
// Barrier-safe for repeated calls (trailing syncthreads).
__device__ __forceinline__ float compute_E(const float* __restrict__ se,
                                           const float* __restrict__ si, int i) {
    int t = threadIdx.x;
    float pref = 0.0f, wtot = 0.0f;
    #pragma unroll
    for (int q = 0; q < NX / 256; ++q) {
        int k = q * 256 + t;
        float rho = DVf * (si[k] - se[k]);
        if (k <= i) pref += rho;
        wtot += rho * (float)(NX - k);
    }
    #pragma unroll
    for (int off = 32; off > 0; off >>= 1) {
        pref += __shfl_down(pref, off, 64);
        wtot += __shfl_down(wtot, off, 64);
    }
    __shared__ float sp_[4], sw_[4];
    int lane = t & 63, wave = t >> 6;
    if (lane == 0) { sp_[wave] = pref; sw_[wave] = wtot; }
    __syncthreads();
    float P = sp_[0] + sp_[1] + sp_[2] + sp_[3];
    float W = sw_[0] + sw_[1] + sw_[2] + sw_[3];
    __syncthreads();
    return DXf * (P - W * (1.0f / (float)NX));
}

// Per-wave tridiagonal solve of one row held in a padded LDS buffer
// (addr(j) = j + (j>>4)). Verified chunk-elim + 2x2-block PCR. Stores to orow.
__device__ __forceinline__ void wave_solve_row(const float* __restrict__ ldsrow,
                                               int i, float lam, float* __restrict__ orow) {
    const float Tdv2   = 1.0f / (DVf * DVf);
    const float inv2dv = 0.5f / DVf;
    int lane = threadIdx.x & 63;

    float xi = DXf * ((float)i + 0.5f) - 0.5f;
    float nu = 1.0f / (1.0f + 0.5f * (expf(60.0f * xi - 20.0f) + expf(-60.0f * xi - 20.0f)));
    float K = DTf * nu * lam;
    float b = 1.0f + 2.0f * K * Tdv2;

    float Dv[16], Av[16], Cv[16];
    int j0 = lane * 16;
    int base = 17 * lane;
    #pragma unroll
    for (int r = 0; r < 16; ++r) {
        int j = j0 + r;
        float d = ldsrow[base + r];
        float a = (j == 0)      ? 0.0f : -K * (Tdv2 - (DVf * ((float)j - 0.5f) - 6.0f) * inv2dv);
        float c = (j == NV - 1) ? 0.0f : -K * (Tdv2 + (DVf * ((float)j + 1.5f) - 6.0f) * inv2dv);
        if (r == 0) {
            float e = frcp(b);
            Dv[0] = e * d;
            Av[0] = e * a;
            Cv[0] = e * c;
        } else {
            float e = frcp(b - a * Cv[r - 1]);
            Dv[r] = e * (d - a * Dv[r - 1]);
            Av[r] = -e * a * Av[r - 1];
            Cv[r] = e * c;
        }
    }
    #pragma unroll
    for (int r = 14; r >= 0; --r) {
        Dv[r] = Dv[r] - Cv[r] * Dv[r + 1];
        Av[r] = Av[r] - Cv[r] * Av[r + 1];
        Cv[r] = -Cv[r] * Cv[r + 1];
    }

    float la = Av[0],  ra = Cv[0],  d0 = Dv[0];
    float lb = Av[15], rb = Cv[15], d1 = Dv[15];

    #pragma unroll
    for (int s = 1; s < 64; s <<= 1) {
        float lb_m = __shfl_up(lb, s, 64);
        float rb_m = __shfl_up(rb, s, 64);
        float d1_m = __shfl_up(d1, s, 64);
        if (lane < s) { lb_m = 0.0f; rb_m = 0.0f; d1_m = 0.0f; }
        float la_p = __shfl_down(la, s, 64);
        float ra_p = __shfl_down(ra, s, 64);
        float d0_p = __shfl_down(d0, s, 64);
        if (lane + s > 63) { la_p = 0.0f; ra_p = 0.0f; d0_p = 0.0f; }

        float m00 = 1.0f - la * rb_m;
        float m01 = -ra * la_p;
        float m10 = -lb * rb_m;
        float m11 = 1.0f - rb * la_p;
        float idet = frcp(m00 * m11 - m01 * m10);

        float Lr0 = -la * lb_m, Lr1 = -lb * lb_m;
        float Rr0 = -ra * ra_p, Rr1 = -rb * ra_p;
        float e0 = d0 - la * d1_m - ra * d0_p;
        float e1 = d1 - lb * d1_m - rb * d0_p;

        la = idet * (m11 * Lr0 - m01 * Lr1);
        lb = idet * (m00 * Lr1 - m10 * Lr0);
        ra = idet * (m11 * Rr0 - m01 * Rr1);
        rb = idet * (m00 * Rr1 - m10 * Rr0);
        d0 = idet * (m11 * e0 - m01 * e1);
        d1 = idet * (m00 * e1 - m10 * e0);
    }
    float zl = __shfl_up(d1, 1, 64);
    if (lane == 0) zl = 0.0f;
    float yr = __shfl_down(d0, 1, 64);
    if (lane == 63) yr = 0.0f;

    float x[16];
    #pragma unroll
    for (int r = 0; r < 16; ++r) x[r] = Dv[r] - Av[r] * zl - Cv[r] * yr;
    #pragma unroll
    for (int q = 0; q < 4; ++q) {
        float4 o;
        o.x = x[4 * q];
        o.y = x[4 * q + 1];
        o.z = x[4 * q + 2];
        o.w = x[4 * q + 3];
        *(float4*)(orow + j0 + 4 * q) = o;
    }
}

// ===== Fused whole-timestep cooperative kernel =====
// grid = 1024 blocks x 256 threads (4 blocks/CU x 256 CU co-resident).
__global__ __launch_bounds__(256, 4) void fused_kernel(const float* __restrict__ fe,
                                                       const float* __restrict__ fi,
                                                       float* __restrict__ fe1,
                                                       float* __restrict__ fi1,
                                                       float* __restrict__ se,
                                                       float* __restrict__ si,
                                                       float* __restrict__ se1,
                                                       float* __restrict__ si1,
                                                       float* __restrict__ out) {
    cg::grid_group grid = cg::this_grid();
    int t = threadIdx.x;
    int lane = t & 63, wave = t >> 6;

    __shared__ float r1[4], r2[4];
    __shared__ float lds_f[4][NV + NV / 16];   // 4 task buffers, padded addr(j)=j+(j>>4)

    // ---- Phase A: row sums of fe, fi (2 rows per block, grid-stride) ----
    for (int i = blockIdx.x * 2; i < NX; i += gridDim.x * 2) {
        #pragma unroll
        for (int q = 0; q < 2; ++q) {
            int row = i + q;
            float4 a4 = *(const float4*)(fe + (size_t)row * NV + 4 * t);
            float4 b4 = *(const float4*)(fi + (size_t)row * NV + 4 * t);
            float a = a4.x + a4.y + a4.z + a4.w;
            float bb = b4.x + b4.y + b4.z + b4.w;
            #pragma unroll
            for (int off = 32; off > 0; off >>= 1) {
                a  += __shfl_down(a, off, 64);
                bb += __shfl_down(bb, off, 64);
            }
            if (lane == 0) { r1[wave] = a; r2[wave] = bb; }
            __syncthreads();
            if (t == 0) {
                se[row] = r1[0] + r1[1] + r1[2] + r1[3];
                si[row] = r2[0] + r2[1] + r2[2] + r2[3];
            }
            __syncthreads();
        }
    }
    grid.sync();

    // ---- Phase B: stage 1, f1 = f + dt*rhs(f); row sums of f1 ----
    for (int i2 = blockIdx.x * 2; i2 < NX; i2 += gridDim.x * 2) {
        float E0 = compute_E(se, si, i2);
        float E1 = compute_E(se, si, i2 + 1);
        #pragma unroll
        for (int k = 0; k < 4; ++k) {
            int i  = i2 + (k >> 1);
            int sp = k & 1;
            float Ec = (sp ? (1.0f / 1836.0f) : -1.0f) * ((k >> 1) ? E1 : E0);
            const float* g = sp ? fi : fe;
            float* o = sp ? fi1 : fe1;
            int j0 = 4 * t;
            float4 f0v, rv;
            rhs4(g, i, j0, Ec, f0v, rv);
            float4 ov;
            ov.x = f0v.x + DTf * rv.x;
            ov.y = f0v.y + DTf * rv.y;
            ov.z = f0v.z + DTf * rv.z;
            ov.w = f0v.w + DTf * rv.w;
            *(float4*)(o + i * NV + j0) = ov;

            float x = ov.x + ov.y + ov.z + ov.w;
            #pragma unroll
            for (int off = 32; off > 0; off >>= 1) x += __shfl_down(x, off, 64);
            if (lane == 0) r1[wave] = x;
            __syncthreads();
            if (t == 0) (sp ? si1 : se1)[i] = r1[0] + r1[1] + r1[2] + r1[3];
            __syncthreads();
        }
    }
    grid.sync();

    // ---- Phase C: stage 2 into 4 LDS buffers, then each wave solves one row ----
    for (int i2 = blockIdx.x * 2; i2 < NX; i2 += gridDim.x * 2) {
        float F0 = compute_E(se1, si1, i2);
        float F1 = compute_E(se1, si1, i2 + 1);
        #pragma unroll
        for (int k = 0; k < 4; ++k) {
            int i  = i2 + (k >> 1);
            int sp = k & 1;
            float Ec = (sp ? (1.0f / 1836.0f) : -1.0f) * ((k >> 1) ? F1 : F0);
            const float* g = sp ? fi1 : fe1;
            const float* h = sp ? fi : fe;
            int j0 = 4 * t;
            float4 f0v, rv;
            rhs4(g, i, j0, Ec, f0v, rv);
            float4 h4 = *(const float4*)(h + i * NV + j0);
            int a = j0 + (j0 >> 4);
            lds_f[k][a]     = 0.5f * h4.x + 0.5f * f0v.x + (0.5f * DTf) * rv.x;
            lds_f[k][a + 1] = 0.5f * h4.y + 0.5f * f0v.y + (0.5f * DTf) * rv.y;
            lds_f[k][a + 2] = 0.5f * h4.z + 0.5f * f0v.z + (0.5f * DTf) * rv.z;
            lds_f[k][a + 3] = 0.5f * h4.w + 0.5f * f0v.w + (0.5f * DTf) * rv.w;
        }
        __syncthreads();
        {
            int k  = wave;                 // each wave solves one task
            int i  = i2 + (k >> 1);
            int sp = k & 1;
            float lam = sp ? 0.1f : 1.0f;
            float* orow = out + ((size_t)sp * NX + i) * NV;
            wave_solve_row(lds_f[k], i, lam, orow);
        }
        __syncthreads();
    }
}

// ===== Fallback path (round-5 verified kernels) =====
__global__ __launch_bounds__(256) void moments_kernel(const float* __restrict__ fe,
                                                      const float* __restrict__ fi,
                                                      float* __restrict__ se,
                                                      float* __restrict__ si) {
    int i = blockIdx.x;
    int t = threadIdx.x;
    float4 a4 = *(const float4*)(fe + (size_t)i * NV + 4 * t);
    float4 b4 = *(const float4*)(fi + (size_t)i * NV + 4 * t);
    float a = a4.x + a4.y + a4.z + a4.w;
    float b = b4.x + b4.y + b4.z + b4.w;
    __shared__ float r1[4], r2[4];
    #pragma unroll
    for (int off = 32; off > 0; off >>= 1) {
        a += __shfl_down(a, off, 64);
        b += __shfl_down(b, off, 64);
    }
    int lane = t & 63, wave = t >> 6;
    if (lane == 0) { r1[wave] = a; r2[wave] = b; }
    __syncthreads();
    if (t == 0) {
        se[i] = r1[0] + r1[1] + r1[2] + r1[3];
        si[i] = r2[0] + r2[1] + r2[2] + r2[3];
    }
}

__global__ __launch_bounds__(256) void stage1_kernel(const float* __restrict__ fe,
                                                     const float* __restrict__ fi,
                                                     const float* __restrict__ se,
                                                     const float* __restrict__ si,
                                                     float* __restrict__ fe1,
                                                     float* __restrict__ fi1,
                                                     float* __restrict__ se1,
                                                     float* __restrict__ si1) {
    int i  = blockIdx.x;
    int sp = blockIdx.y;
    const float* g = sp ? fi : fe;
    float* out = sp ? fi1 : fe1;
    float zoa = sp ? (1.0f / 1836.0f) : -1.0f;
    float Ec = zoa * compute_E(se, si, i);
    int t = threadIdx.x;
    int j0 = 4 * t;

    float4 f0v, rv;
    rhs4(g, i, j0, Ec, f0v, rv);
    float4 o;
    o.x = f0v.x + DTf * rv.x;
    o.y = f0v.y + DTf * rv.y;
    o.z = f0v.z + DTf * rv.z;
    o.w = f0v.w + DTf * rv.w;
    *(float4*)(out + i * NV + j0) = o;

    float x = o.x + o.y + o.z + o.w;
    #pragma unroll
    for (int off = 32; off > 0; off >>= 1) x += __shfl_down(x, off, 64);
    __shared__ float sred[4];
    int lane = t & 63, wave = t >> 6;
    if (lane == 0) sred[wave] = x;
    __syncthreads();
    if (t == 0) { (sp ? si1 : se1)[i] = sred[0] + sred[1] + sred[2] + sred[3]; }
}

__global__ __launch_bounds__(256) void stage2_collide_kernel(const float* __restrict__ fe,
                                                             const float* __restrict__ fi,
                                                             const float* __restrict__ fe1,
                                                             const float* __restrict__ fi1,
                                                             const float* __restrict__ se1,
                                                             const float* __restrict__ si1,
                                                             float* __restrict__ out) {
    int i  = blockIdx.x;
    int sp = blockIdx.y;
    const float* h = sp ? fi : fe;
    const float* g = sp ? fi1 : fe1;
    float* orow = out + ((size_t)sp * NX + i) * NV;
    float zoa = sp ? (1.0f / 1836.0f) : -1.0f;
    float lam = sp ? 0.1f : 1.0f;
    float Ec = zoa * compute_E(se1, si1, i);
    int t = threadIdx.x;
    int wave = t >> 6;

    __shared__ float lds_f[NV + NV / 16];
    {
        int j0 = 4 * t;
        float4 f0v, rv;
        rhs4(g, i, j0, Ec, f0v, rv);
        float4 h4 = *(const float4*)(h + i * NV + j0);
        int a = j0 + (j0 >> 4);
        lds_f[a]     = 0.5f * h4.x + 0.5f * f0v.x + (0.5f * DTf) * rv.x;
        lds_f[a + 1] = 0.5f * h4.y + 0.5f * f0v.y + (0.5f * DTf) * rv.y;
        lds_f[a + 2] = 0.5f * h4.z + 0.5f * f0v.z + (0.5f * DTf) * rv.z;
        lds_f[a + 3] = 0.5f * h4.w + 0.5f * f0v.w + (0.5f * DTf) * rv.w;
    }
    __syncthreads();
    if (wave != 0) return;
    wave_solve_row(lds_f, i, lam, orow);
}

extern "C" void kernel_launch(void* const* d_in, const int* in_sizes, int n_in,
                              void* d_out, int out_size, void* d_ws, size_t ws_size,
                              hipStream_t stream) {
    const float* fe = (const float*)d_in[0];
    const float* fi = (const float*)d_in[1];
    float* out = (float*)d_out;
    const size_t P = (size_t)NX * NV;

    float* fe1 = (float*)d_ws;
    float* fi1 = fe1 + P;
    float* se  = fi1 + P;
    float* si  = se + NX;
    float* se1 = si + NX;
    float* si1 = se1 + NX;

    void* args[] = {(void*)&fe, (void*)&fi, (void*)&fe1, (void*)&fi1,
                    (void*)&se, (void*)&si, (void*)&se1, (void*)&si1, (void*)&out};
    hipError_t err = hipLaunchCooperativeKernel((const void*)fused_kernel,
                                                dim3(1024), dim3(256),
                                                args, 0, stream);
    if (err != hipSuccess) {
        // deterministic fallback: round-5 three-kernel path
        dim3 rgrid(NX, 2);
        moments_kernel<<<NX, 256, 0, stream>>>(fe, fi, se, si);
        stage1_kernel<<<rgrid, 256, 0, stream>>>(fe, fi, se, si, fe1, fi1, se1, si1);
        stage2_collide_kernel<<<rgrid, 256, 0, stream>>>(fe, fi, fe1, fi1, se1, si1, out);
    }
}

// Round 8
// 116.520 us; speedup vs baseline: 2.6873x; 2.6873x over previous
//
#include <hip/hip_runtime.h>
#include <math.h>

#define NX 2048
#define NV 1024
static constexpr float DXf   = 1.0f / 2048.0f;
static constexpr float DVf   = 12.0f / 1024.0f;
static constexpr float DTf   = 0.001f;
static constexpr float INV_DX = 2048.0f;
static constexpr float INV_DV = 1024.0f / 12.0f;

typedef float vfloat4 __attribute__((ext_vector_type(4)));   // native vector for nt-store

__device__ __forceinline__ float minmod_f(float a, float b) {
    return (a * b > 0.0f) ? (a > 0.0f ? fminf(a, b) : fmaxf(a, b)) : 0.0f;
}

__device__ __forceinline__ float frcp(float x) {
    float r = __builtin_amdgcn_rcpf(x);
    return r * (2.0f - x * r);
}

// Vectorized MUSCL rhs for 4 contiguous cells j0..j0+3 (j0 % 4 == 0).
__device__ __forceinline__ void rhs4(const float* __restrict__ g, int i, int j0, float Ec,
                                     float4& f0v, float4& rv) {
    const float* rowc = g + i * NV;
    const float* rm1  = g + (((i - 1) & (NX - 1)) * NV);
    const float* rm2  = g + (((i - 2) & (NX - 1)) * NV);
    const float* rp1  = g + (((i + 1) & (NX - 1)) * NV);
    const float* rp2  = g + (((i + 2) & (NX - 1)) * NV);

    float4 c   = *(const float4*)(rowc + j0);
    float4 xm1 = *(const float4*)(rm1 + j0);
    float4 xm2 = *(const float4*)(rm2 + j0);
    float4 xp1 = *(const float4*)(rp1 + j0);
    float4 xp2 = *(const float4*)(rp2 + j0);
    float4 lm = make_float4(0.f, 0.f, 0.f, 0.f);
    float4 rp = make_float4(0.f, 0.f, 0.f, 0.f);
    if (j0 >= 4)      lm = *(const float4*)(rowc + j0 - 4);
    if (j0 <= NV - 8) rp = *(const float4*)(rowc + j0 + 4);

    float vals[8] = {lm.z, lm.w, c.x, c.y, c.z, c.w, rp.x, rp.y};
    const float* cc   = (const float*)&c;
    const float* am1  = (const float*)&xm1;
    const float* am2  = (const float*)&xm2;
    const float* ap1  = (const float*)&xp1;
    const float* ap2  = (const float*)&xp2;
    float* f0o = (float*)&f0v;
    float* ro  = (float*)&rv;

    #pragma unroll
    for (int k = 0; k < 4; ++k) {
        float f0  = cc[k];
        float fm1 = am1[k], fm2 = am2[k], fp1 = ap1[k], fp2 = ap2[k];

        float v = DVf * ((float)(j0 + k) + 0.5f) - 6.0f;
        float dm1 = fm1 - fm2, d0 = f0 - fm1, dp1 = fp1 - f0, dp2 = fp2 - fp1;
        float sm1 = minmod_f(dm1, d0);
        float s0  = minmod_f(d0, dp1);
        float sp1 = minmod_f(dp1, dp2);
        float PhiM, PhiP;
        if (v > 0.0f) {
            PhiM = (fm1 + 0.5f * sm1) * v;
            PhiP = (f0  + 0.5f * s0 ) * v;
        } else {
            PhiM = (f0  - 0.5f * s0 ) * v;
            PhiP = (fp1 - 0.5f * sp1) * v;
        }
        float vdfdx = (PhiP - PhiM) * INV_DX;

        float gm2 = vals[k], gm1 = vals[k + 1], gp1 = vals[k + 3], gp2 = vals[k + 4];
        float em1 = gm1 - gm2, e0 = f0 - gm1, ep1 = gp1 - f0, ep2 = gp2 - gp1;
        float tm1 = minmod_f(em1, e0);
        float t0  = minmod_f(e0, ep1);
        float tp1 = minmod_f(ep1, ep2);
        float GM, GP;
        if (Ec > 0.0f) {
            GM = (gm1 + 0.5f * tm1) * Ec;
            GP = (f0  + 0.5f * t0 ) * Ec;
        } else {
            GM = (f0  - 0.5f * t0 ) * Ec;
            GP = (gp1 - 0.5f * tp1) * Ec;
        }
        float Edfdv = (GP - GM) * INV_DV;

        f0o[k] = f0;
        ro[k]  = -vdfdx - Edfdv;
    }
}

// E[i] = DX*(P_i - W/NX), P_i = sum_{k<=i} rho_k, W = sum_k rho_k*(NX-k).
__device__ __forceinline__ float compute_E(const float* __restrict__ se,
                                           const float* __restrict__ si, int i) {
    int t = threadIdx.x;
    float pref = 0.0f, wtot = 0.0f;
    #pragma unroll
    for (int q = 0; q < NX / 256; ++q) {
        int k = q * 256 + t;
        float rho = DVf * (si[k] - se[k]);
        if (k <= i) pref += rho;
        wtot += rho * (float)(NX - k);
    }
    #pragma unroll
    for (int off = 32; off > 0; off >>= 1) {
        pref += __shfl_down(pref, off, 64);
        wtot += __shfl_down(wtot, off, 64);
    }
    __shared__ float sp_[4], sw_[4];
    int lane = t & 63, wave = t >> 6;
    if (lane == 0) { sp_[wave] = pref; sw_[wave] = wtot; }
    __syncthreads();
    float P = sp_[0] + sp_[1] + sp_[2] + sp_[3];
    float W = sw_[0] + sw_[1] + sw_[2] + sw_[3];
    return DXf * (P - W * (1.0f / (float)NX));
}

// se[i] = sum_j fe[i,j]; si[i] = sum_j fi[i,j]
__global__ __launch_bounds__(256) void moments_kernel(const float* __restrict__ fe,
                                                      const float* __restrict__ fi,
                                                      float* __restrict__ se,
                                                      float* __restrict__ si) {
    int i = blockIdx.x;
    int t = threadIdx.x;
    float4 a4 = *(const float4*)(fe + (size_t)i * NV + 4 * t);
    float4 b4 = *(const float4*)(fi + (size_t)i * NV + 4 * t);
    float a = a4.x + a4.y + a4.z + a4.w;
    float b = b4.x + b4.y + b4.z + b4.w;
    __shared__ float r1[4], r2[4];
    #pragma unroll
    for (int off = 32; off > 0; off >>= 1) {
        a += __shfl_down(a, off, 64);
        b += __shfl_down(b, off, 64);
    }
    int lane = t & 63, wave = t >> 6;
    if (lane == 0) { r1[wave] = a; r2[wave] = b; }
    __syncthreads();
    if (t == 0) {
        se[i] = r1[0] + r1[1] + r1[2] + r1[3];
        si[i] = r2[0] + r2[1] + r2[2] + r2[3];
    }
}

// Stage 1: f1 = f + dt*rhs(f); E computed in-block; writes row sums of f1.
__global__ __launch_bounds__(256) void stage1_kernel(const float* __restrict__ fe,
                                                     const float* __restrict__ fi,
                                                     const float* __restrict__ se,
                                                     const float* __restrict__ si,
                                                     float* __restrict__ fe1,
                                                     float* __restrict__ fi1,
                                                     float* __restrict__ se1,
                                                     float* __restrict__ si1) {
    int i  = blockIdx.x;
    int sp = blockIdx.y;
    const float* g = sp ? fi : fe;
    float* out = sp ? fi1 : fe1;
    float zoa = sp ? (1.0f / 1836.0f) : -1.0f;
    float Ec = zoa * compute_E(se, si, i);
    int t = threadIdx.x;
    int j0 = 4 * t;

    float4 f0v, rv;
    rhs4(g, i, j0, Ec, f0v, rv);
    float4 o;
    o.x = f0v.x + DTf * rv.x;
    o.y = f0v.y + DTf * rv.y;
    o.z = f0v.z + DTf * rv.z;
    o.w = f0v.w + DTf * rv.w;
    *(float4*)(out + i * NV + j0) = o;

    float x = o.x + o.y + o.z + o.w;
    #pragma unroll
    for (int off = 32; off > 0; off >>= 1) x += __shfl_down(x, off, 64);
    __shared__ float sred[4];
    int lane = t & 63, wave = t >> 6;
    if (lane == 0) sred[wave] = x;
    __syncthreads();
    if (t == 0) { (sp ? si1 : se1)[i] = sred[0] + sred[1] + sred[2] + sred[3]; }
}

// Stage 2 + implicit LBO collide, fused. One block (256 thr) per (row, sp).
__global__ __launch_bounds__(256) void stage2_collide_kernel(const float* __restrict__ fe,
                                                             const float* __restrict__ fi,
                                                             const float* __restrict__ fe1,
                                                             const float* __restrict__ fi1,
                                                             const float* __restrict__ se1,
                                                             const float* __restrict__ si1,
                                                             float* __restrict__ out) {
    const float Tdv2   = 1.0f / (DVf * DVf);
    const float inv2dv = 0.5f / DVf;

    int i  = blockIdx.x;
    int sp = blockIdx.y;
    const float* h = sp ? fi : fe;
    const float* g = sp ? fi1 : fe1;
    float* orow = out + ((size_t)sp * NX + i) * NV;
    float zoa = sp ? (1.0f / 1836.0f) : -1.0f;
    float lam = sp ? 0.1f : 1.0f;
    float Ec = zoa * compute_E(se1, si1, i);
    int t = threadIdx.x;
    int lane = t & 63;
    int wave = t >> 6;

    __shared__ float lds_f[NV + NV / 16];   // padded: addr(j) = j + (j>>4)

    {
        int j0 = 4 * t;
        float4 f0v, rv;
        rhs4(g, i, j0, Ec, f0v, rv);
        float4 h4 = *(const float4*)(h + i * NV + j0);
        int a = j0 + (j0 >> 4);
        lds_f[a]     = 0.5f * h4.x + 0.5f * f0v.x + (0.5f * DTf) * rv.x;
        lds_f[a + 1] = 0.5f * h4.y + 0.5f * f0v.y + (0.5f * DTf) * rv.y;
        lds_f[a + 2] = 0.5f * h4.z + 0.5f * f0v.z + (0.5f * DTf) * rv.z;
        lds_f[a + 3] = 0.5f * h4.w + 0.5f * f0v.w + (0.5f * DTf) * rv.w;
    }
    __syncthreads();
    if (wave != 0) return;

    float xi = DXf * ((float)i + 0.5f) - 0.5f;
    float nu = 1.0f / (1.0f + 0.5f * (expf(60.0f * xi - 20.0f) + expf(-60.0f * xi - 20.0f)));
    float K = DTf * nu * lam;
    float b = 1.0f + 2.0f * K * Tdv2;

    float Dv[16], Av[16], Cv[16];
    int j0 = lane * 16;
    int base = 17 * lane;
    #pragma unroll
    for (int r = 0; r < 16; ++r) {
        int j = j0 + r;
        float d = lds_f[base + r];
        float a = (j == 0)      ? 0.0f : -K * (Tdv2 - (DVf * ((float)j - 0.5f) - 6.0f) * inv2dv);
        float c = (j == NV - 1) ? 0.0f : -K * (Tdv2 + (DVf * ((float)j + 1.5f) - 6.0f) * inv2dv);
        if (r == 0) {
            float e = frcp(b);
            Dv[0] = e * d;
            Av[0] = e * a;
            Cv[0] = e * c;
        } else {
            float e = frcp(b - a * Cv[r - 1]);
            Dv[r] = e * (d - a * Dv[r - 1]);
            Av[r] = -e * a * Av[r - 1];
            Cv[r] = e * c;
        }
    }
    #pragma unroll
    for (int r = 14; r >= 0; --r) {
        Dv[r] = Dv[r] - Cv[r] * Dv[r + 1];
        Av[r] = Av[r] - Cv[r] * Av[r + 1];
        Cv[r] = -Cv[r] * Cv[r + 1];
    }

    // interface system per lane t: u_t + L_t u_{t-1} + R_t u_{t+1} = d_t
    float la = Av[0],  ra = Cv[0],  d0 = Dv[0];
    float lb = Av[15], rb = Cv[15], d1 = Dv[15];

    #pragma unroll
    for (int s = 1; s < 64; s <<= 1) {
        float lb_m = __shfl_up(lb, s, 64);
        float rb_m = __shfl_up(rb, s, 64);
        float d1_m = __shfl_up(d1, s, 64);
        if (lane < s) { lb_m = 0.0f; rb_m = 0.0f; d1_m = 0.0f; }
        float la_p = __shfl_down(la, s, 64);
        float ra_p = __shfl_down(ra, s, 64);
        float d0_p = __shfl_down(d0, s, 64);
        if (lane + s > 63) { la_p = 0.0f; ra_p = 0.0f; d0_p = 0.0f; }

        float m00 = 1.0f - la * rb_m;
        float m01 = -ra * la_p;
        float m10 = -lb * rb_m;
        float m11 = 1.0f - rb * la_p;
        float idet = frcp(m00 * m11 - m01 * m10);

        float Lr0 = -la * lb_m, Lr1 = -lb * lb_m;
        float Rr0 = -ra * ra_p, Rr1 = -rb * ra_p;
        float e0 = d0 - la * d1_m - ra * d0_p;
        float e1 = d1 - lb * d1_m - rb * d0_p;

        la = idet * (m11 * Lr0 - m01 * Lr1);
        lb = idet * (m00 * Lr1 - m10 * Lr0);
        ra = idet * (m11 * Rr0 - m01 * Rr1);
        rb = idet * (m00 * Rr1 - m10 * Rr0);
        d0 = idet * (m11 * e0 - m01 * e1);
        d1 = idet * (m00 * e1 - m10 * e0);
    }
    float zl = __shfl_up(d1, 1, 64);
    if (lane == 0) zl = 0.0f;
    float yr = __shfl_down(d0, 1, 64);
    if (lane == 63) yr = 0.0f;

    float x[16];
    #pragma unroll
    for (int r = 0; r < 16; ++r) x[r] = Dv[r] - Av[r] * zl - Cv[r] * yr;
    #pragma unroll
    for (int q = 0; q < 4; ++q) {
        vfloat4 o;
        o.x = x[4 * q];
        o.y = x[4 * q + 1];
        o.z = x[4 * q + 2];
        o.w = x[4 * q + 3];
        // out is never re-read: nontemporal store keeps L2 for fe/fi/f1 lines
        __builtin_nontemporal_store(o, (vfloat4*)(orow + j0 + 4 * q));
    }
}

extern "C" void kernel_launch(void* const* d_in, const int* in_sizes, int n_in,
                              void* d_out, int out_size, void* d_ws, size_t ws_size,
                              hipStream_t stream) {
    const float* fe = (const float*)d_in[0];
    const float* fi = (const float*)d_in[1];
    float* out = (float*)d_out;
    const size_t P = (size_t)NX * NV;

    float* fe1 = (float*)d_ws;
    float* fi1 = fe1 + P;
    float* se  = fi1 + P;
    float* si  = se + NX;
    float* se1 = si + NX;
    float* si1 = se1 + NX;

    dim3 rgrid(NX, 2);

    moments_kernel<<<NX, 256, 0, stream>>>(fe, fi, se, si);
    stage1_kernel<<<rgrid, 256, 0, stream>>>(fe, fi, se, si, fe1, fi1, se1, si1);
    stage2_collide_kernel<<<rgrid, 256, 0, stream>>>(fe, fi, fe1, fi1, se1, si1, out);
}

// Round 9
// 112.212 us; speedup vs baseline: 2.7904x; 1.0384x over previous
//
#include <hip/hip_runtime.h>
#include <math.h>

#define NX 2048
#define NV 1024
static constexpr float DXf   = 1.0f / 2048.0f;
static constexpr float DVf   = 12.0f / 1024.0f;
static constexpr float DTf   = 0.001f;
static constexpr float INV_DX = 2048.0f;
static constexpr float INV_DV = 1024.0f / 12.0f;

__device__ __forceinline__ float minmod_f(float a, float b) {
    return (a * b > 0.0f) ? (a > 0.0f ? fminf(a, b) : fmaxf(a, b)) : 0.0f;
}

__device__ __forceinline__ float frcp(float x) {
    float r = __builtin_amdgcn_rcpf(x);
    return r * (2.0f - x * r);
}

// Vectorized MUSCL rhs for 4 contiguous cells j0..j0+3 (j0 % 4 == 0).
__device__ __forceinline__ void rhs4(const float* __restrict__ g, int i, int j0, float Ec,
                                     float4& f0v, float4& rv) {
    const float* rowc = g + i * NV;
    const float* rm1  = g + (((i - 1) & (NX - 1)) * NV);
    const float* rm2  = g + (((i - 2) & (NX - 1)) * NV);
    const float* rp1  = g + (((i + 1) & (NX - 1)) * NV);
    const float* rp2  = g + (((i + 2) & (NX - 1)) * NV);

    float4 c   = *(const float4*)(rowc + j0);
    float4 xm1 = *(const float4*)(rm1 + j0);
    float4 xm2 = *(const float4*)(rm2 + j0);
    float4 xp1 = *(const float4*)(rp1 + j0);
    float4 xp2 = *(const float4*)(rp2 + j0);
    float4 lm = make_float4(0.f, 0.f, 0.f, 0.f);
    float4 rp = make_float4(0.f, 0.f, 0.f, 0.f);
    if (j0 >= 4)      lm = *(const float4*)(rowc + j0 - 4);
    if (j0 <= NV - 8) rp = *(const float4*)(rowc + j0 + 4);

    float vals[8] = {lm.z, lm.w, c.x, c.y, c.z, c.w, rp.x, rp.y};
    const float* cc   = (const float*)&c;
    const float* am1  = (const float*)&xm1;
    const float* am2  = (const float*)&xm2;
    const float* ap1  = (const float*)&xp1;
    const float* ap2  = (const float*)&xp2;
    float* f0o = (float*)&f0v;
    float* ro  = (float*)&rv;

    #pragma unroll
    for (int k = 0; k < 4; ++k) {
        float f0  = cc[k];
        float fm1 = am1[k], fm2 = am2[k], fp1 = ap1[k], fp2 = ap2[k];

        float v = DVf * ((float)(j0 + k) + 0.5f) - 6.0f;
        float dm1 = fm1 - fm2, d0 = f0 - fm1, dp1 = fp1 - f0, dp2 = fp2 - fp1;
        float sm1 = minmod_f(dm1, d0);
        float s0  = minmod_f(d0, dp1);
        float sp1 = minmod_f(dp1, dp2);
        float PhiM, PhiP;
        if (v > 0.0f) {
            PhiM = (fm1 + 0.5f * sm1) * v;
            PhiP = (f0  + 0.5f * s0 ) * v;
        } else {
            PhiM = (f0  - 0.5f * s0 ) * v;
            PhiP = (fp1 - 0.5f * sp1) * v;
        }
        float vdfdx = (PhiP - PhiM) * INV_DX;

        float gm2 = vals[k], gm1 = vals[k + 1], gp1 = vals[k + 3], gp2 = vals[k + 4];
        float em1 = gm1 - gm2, e0 = f0 - gm1, ep1 = gp1 - f0, ep2 = gp2 - gp1;
        float tm1 = minmod_f(em1, e0);
        float t0  = minmod_f(e0, ep1);
        float tp1 = minmod_f(ep1, ep2);
        float GM, GP;
        if (Ec > 0.0f) {
            GM = (gm1 + 0.5f * tm1) * Ec;
            GP = (f0  + 0.5f * t0 ) * Ec;
        } else {
            GM = (f0  - 0.5f * t0 ) * Ec;
            GP = (gp1 - 0.5f * tp1) * Ec;
        }
        float Edfdv = (GP - GM) * INV_DV;

        f0o[k] = f0;
        ro[k]  = -vdfdx - Edfdv;
    }
}

// E[i] = DX*(P_i - W/NX), P_i = sum_{k<=i} rho_k, W = sum_k rho_k*(NX-k).
__device__ __forceinline__ float compute_E(const float* __restrict__ se,
                                           const float* __restrict__ si, int i) {
    int t = threadIdx.x;
    float pref = 0.0f, wtot = 0.0f;
    #pragma unroll
    for (int q = 0; q < NX / 256; ++q) {
        int k = q * 256 + t;
        float rho = DVf * (si[k] - se[k]);
        if (k <= i) pref += rho;
        wtot += rho * (float)(NX - k);
    }
    #pragma unroll
    for (int off = 32; off > 0; off >>= 1) {
        pref += __shfl_down(pref, off, 64);
        wtot += __shfl_down(wtot, off, 64);
    }
    __shared__ float sp_[4], sw_[4];
    int lane = t & 63, wave = t >> 6;
    if (lane == 0) { sp_[wave] = pref; sw_[wave] = wtot; }
    __syncthreads();
    float P = sp_[0] + sp_[1] + sp_[2] + sp_[3];
    float W = sw_[0] + sw_[1] + sw_[2] + sw_[3];
    return DXf * (P - W * (1.0f / (float)NX));
}

// se[i] = sum_j fe[i,j]; si[i] = sum_j fi[i,j]
__global__ __launch_bounds__(256) void moments_kernel(const float* __restrict__ fe,
                                                      const float* __restrict__ fi,
                                                      float* __restrict__ se,
                                                      float* __restrict__ si) {
    int i = blockIdx.x;
    int t = threadIdx.x;
    float4 a4 = *(const float4*)(fe + (size_t)i * NV + 4 * t);
    float4 b4 = *(const float4*)(fi + (size_t)i * NV + 4 * t);
    float a = a4.x + a4.y + a4.z + a4.w;
    float b = b4.x + b4.y + b4.z + b4.w;
    __shared__ float r1[4], r2[4];
    #pragma unroll
    for (int off = 32; off > 0; off >>= 1) {
        a += __shfl_down(a, off, 64);
        b += __shfl_down(b, off, 64);
    }
    int lane = t & 63, wave = t >> 6;
    if (lane == 0) { r1[wave] = a; r2[wave] = b; }
    __syncthreads();
    if (t == 0) {
        se[i] = r1[0] + r1[1] + r1[2] + r1[3];
        si[i] = r2[0] + r2[1] + r2[2] + r2[3];
    }
}

// Stage 1: f1 = f + dt*rhs(f); E computed in-block; writes row sums of f1.
__global__ __launch_bounds__(256) void stage1_kernel(const float* __restrict__ fe,
                                                     const float* __restrict__ fi,
                                                     const float* __restrict__ se,
                                                     const float* __restrict__ si,
                                                     float* __restrict__ fe1,
                                                     float* __restrict__ fi1,
                                                     float* __restrict__ se1,
                                                     float* __restrict__ si1) {
    int i  = blockIdx.x;
    int sp = blockIdx.y;
    const float* g = sp ? fi : fe;
    float* out = sp ? fi1 : fe1;
    float zoa = sp ? (1.0f / 1836.0f) : -1.0f;
    float Ec = zoa * compute_E(se, si, i);
    int t = threadIdx.x;
    int j0 = 4 * t;

    float4 f0v, rv;
    rhs4(g, i, j0, Ec, f0v, rv);
    float4 o;
    o.x = f0v.x + DTf * rv.x;
    o.y = f0v.y + DTf * rv.y;
    o.z = f0v.z + DTf * rv.z;
    o.w = f0v.w + DTf * rv.w;
    *(float4*)(out + i * NV + j0) = o;

    float x = o.x + o.y + o.z + o.w;
    #pragma unroll
    for (int off = 32; off > 0; off >>= 1) x += __shfl_down(x, off, 64);
    __shared__ float sred[4];
    int lane = t & 63, wave = t >> 6;
    if (lane == 0) sred[wave] = x;
    __syncthreads();
    if (t == 0) { (sp ? si1 : se1)[i] = sred[0] + sred[1] + sred[2] + sred[3]; }
}

// Stage 2 + implicit LBO collide, fused. One block (256 thr) per (row, sp).
__global__ __launch_bounds__(256) void stage2_collide_kernel(const float* __restrict__ fe,
                                                             const float* __restrict__ fi,
                                                             const float* __restrict__ fe1,
                                                             const float* __restrict__ fi1,
                                                             const float* __restrict__ se1,
                                                             const float* __restrict__ si1,
                                                             float* __restrict__ out) {
    const float Tdv2   = 1.0f / (DVf * DVf);
    const float inv2dv = 0.5f / DVf;

    int i  = blockIdx.x;
    int sp = blockIdx.y;
    const float* h = sp ? fi : fe;
    const float* g = sp ? fi1 : fe1;
    float* orow = out + ((size_t)sp * NX + i) * NV;
    float zoa = sp ? (1.0f / 1836.0f) : -1.0f;
    float lam = sp ? 0.1f : 1.0f;
    float Ec = zoa * compute_E(se1, si1, i);
    int t = threadIdx.x;
    int lane = t & 63;
    int wave = t >> 6;

    __shared__ float lds_f[NV + NV / 16];   // padded: addr(j) = j + (j>>4)

    {
        int j0 = 4 * t;
        float4 f0v, rv;
        rhs4(g, i, j0, Ec, f0v, rv);
        float4 h4 = *(const float4*)(h + i * NV + j0);
        int a = j0 + (j0 >> 4);
        lds_f[a]     = 0.5f * h4.x + 0.5f * f0v.x + (0.5f * DTf) * rv.x;
        lds_f[a + 1] = 0.5f * h4.y + 0.5f * f0v.y + (0.5f * DTf) * rv.y;
        lds_f[a + 2] = 0.5f * h4.z + 0.5f * f0v.z + (0.5f * DTf) * rv.z;
        lds_f[a + 3] = 0.5f * h4.w + 0.5f * f0v.w + (0.5f * DTf) * rv.w;
    }
    __syncthreads();
    if (wave != 0) return;

    float xi = DXf * ((float)i + 0.5f) - 0.5f;
    float nu = 1.0f / (1.0f + 0.5f * (expf(60.0f * xi - 20.0f) + expf(-60.0f * xi - 20.0f)));
    float K = DTf * nu * lam;
    float b = 1.0f + 2.0f * K * Tdv2;

    float Dv[16], Av[16], Cv[16];
    int j0 = lane * 16;
    int base = 17 * lane;
    #pragma unroll
    for (int r = 0; r < 16; ++r) {
        int j = j0 + r;
        float d = lds_f[base + r];
        float a = (j == 0)      ? 0.0f : -K * (Tdv2 - (DVf * ((float)j - 0.5f) - 6.0f) * inv2dv);
        float c = (j == NV - 1) ? 0.0f : -K * (Tdv2 + (DVf * ((float)j + 1.5f) - 6.0f) * inv2dv);
        if (r == 0) {
            float e = frcp(b);
            Dv[0] = e * d;
            Av[0] = e * a;
            Cv[0] = e * c;
        } else {
            float e = frcp(b - a * Cv[r - 1]);
            Dv[r] = e * (d - a * Dv[r - 1]);
            Av[r] = -e * a * Av[r - 1];
            Cv[r] = e * c;
        }
    }
    #pragma unroll
    for (int r = 14; r >= 0; --r) {
        Dv[r] = Dv[r] - Cv[r] * Dv[r + 1];
        Av[r] = Av[r] - Cv[r] * Av[r + 1];
        Cv[r] = -Cv[r] * Cv[r + 1];
    }

    // interface system per lane t: u_t + L_t u_{t-1} + R_t u_{t+1} = d_t
    float la = Av[0],  ra = Cv[0],  d0 = Dv[0];
    float lb = Av[15], rb = Cv[15], d1 = Dv[15];

    #pragma unroll
    for (int s = 1; s < 64; s <<= 1) {
        float lb_m = __shfl_up(lb, s, 64);
        float rb_m = __shfl_up(rb, s, 64);
        float d1_m = __shfl_up(d1, s, 64);
        if (lane < s) { lb_m = 0.0f; rb_m = 0.0f; d1_m = 0.0f; }
        float la_p = __shfl_down(la, s, 64);
        float ra_p = __shfl_down(ra, s, 64);
        float d0_p = __shfl_down(d0, s, 64);
        if (lane + s > 63) { la_p = 0.0f; ra_p = 0.0f; d0_p = 0.0f; }

        float m00 = 1.0f - la * rb_m;
        float m01 = -ra * la_p;
        float m10 = -lb * rb_m;
        float m11 = 1.0f - rb * la_p;
        float idet = frcp(m00 * m11 - m01 * m10);

        float Lr0 = -la * lb_m, Lr1 = -lb * lb_m;
        float Rr0 = -ra * ra_p, Rr1 = -rb * ra_p;
        float e0 = d0 - la * d1_m - ra * d0_p;
        float e1 = d1 - lb * d1_m - rb * d0_p;

        la = idet * (m11 * Lr0 - m01 * Lr1);
        lb = idet * (m00 * Lr1 - m10 * Lr0);
        ra = idet * (m11 * Rr0 - m01 * Rr1);
        rb = idet * (m00 * Rr1 - m10 * Rr0);
        d0 = idet * (m11 * e0 - m01 * e1);
        d1 = idet * (m00 * e1 - m10 * e0);
    }
    float zl = __shfl_up(d1, 1, 64);
    if (lane == 0) zl = 0.0f;
    float yr = __shfl_down(d0, 1, 64);
    if (lane == 63) yr = 0.0f;

    float x[16];
    #pragma unroll
    for (int r = 0; r < 16; ++r) x[r] = Dv[r] - Av[r] * zl - Cv[r] * yr;
    #pragma unroll
    for (int q = 0; q < 4; ++q) {
        float4 o;
        o.x = x[4 * q];
        o.y = x[4 * q + 1];
        o.z = x[4 * q + 2];
        o.w = x[4 * q + 3];
        *(float4*)(orow + j0 + 4 * q) = o;
    }
}

extern "C" void kernel_launch(void* const* d_in, const int* in_sizes, int n_in,
                              void* d_out, int out_size, void* d_ws, size_t ws_size,
                              hipStream_t stream) {
    const float* fe = (const float*)d_in[0];
    const float* fi = (const float*)d_in[1];
    float* out = (float*)d_out;
    const size_t P = (size_t)NX * NV;

    float* fe1 = (float*)d_ws;
    float* fi1 = fe1 + P;
    float* se  = fi1 + P;
    float* si  = se + NX;
    float* se1 = si + NX;
    float* si1 = se1 + NX;

    dim3 rgrid(NX, 2);

    moments_kernel<<<NX, 256, 0, stream>>>(fe, fi, se, si);
    stage1_kernel<<<rgrid, 256, 0, stream>>>(fe, fi, se, si, fe1, fi1, se1, si1);
    stage2_collide_kernel<<<rgrid, 256, 0, stream>>>(fe, fi, fe1, fi1, se1, si1, out);
}